// Round 8
// baseline (169.132 us; speedup 1.0000x reference)
//
#include <hip/hip_runtime.h>

// CausalSelfAttention  B=2, T=2048, C=768, H=12, hs=64 — round 8.
// * attn rewritten on mfma_f32_32x32x16_bf16: 4 waves = 2 q-halves x 2
//   k-halves of a 64x64 tile; LDS fragment reads HALVE (64->32KB/block-tile,
//   the round-7 bottleneck). K staged at rho^-1(k)=16k2+8k4+4k3+(k&3) so S
//   registers are exactly the PV B-fragments (p0={s0-3,s8-11}, p1={s4-7,
//   s12-15}). Softmax fully lane-local (lane owns one q); defer-max branch
//   pair-syncs m via one shfl_xor(32); k-half waves merged via LDS epilogue.
//   m init -1e4 so fully-masked diagonal sub-blocks give p=0 (not exp(0)).
// * gemm / prep / detect / schedule: round-7 verified, unchanged.

#define BB 2
#define TT 2048
#define CC 768
#define C3 2304
#define HH 12
#define DD 64
#define MM 4096   // B*T

typedef unsigned short u16;
typedef unsigned int u32;
typedef __attribute__((ext_vector_type(8))) u16 u16x8;
typedef __attribute__((ext_vector_type(8))) __bf16 bf16x8;
typedef __attribute__((ext_vector_type(4))) float f32x4;
typedef __attribute__((ext_vector_type(16))) float f32x16;

__device__ __forceinline__ float u2f(u16 u) {
    union { u32 i; float f; } c; c.i = ((u32)u) << 16; return c.f;
}
__device__ __forceinline__ u16 f2u(float f) {
    union { float f; u32 i; } c; c.f = f;
    u32 x = c.i;
    return (u16)((x + 0x7FFFu + ((x >> 16) & 1u)) >> 16);  // RNE
}
__device__ __forceinline__ u16 f2b(float f) {              // RNE via v_cvt
    __bf16 h = (__bf16)f; return __builtin_bit_cast(u16, h);
}
__device__ __forceinline__ bf16x8 ldsb8(const u16* p) {
    return __builtin_bit_cast(bf16x8, *(const u16x8*)p);
}
__device__ __forceinline__ f32x4 mfma16(bf16x8 a, bf16x8 b, f32x4 c) {
    return __builtin_amdgcn_mfma_f32_16x16x32_bf16(a, b, c, 0, 0, 0);
}
__device__ __forceinline__ f32x16 mfma32(bf16x8 a, bf16x8 b, f32x16 c) {
    return __builtin_amdgcn_mfma_f32_32x32x16_bf16(a, b, c, 0, 0, 0);
}
typedef __attribute__((address_space(1))) const u32 gu32;
typedef __attribute__((address_space(3))) u32 lu32;
__device__ __forceinline__ void gload16(const u16* gp, u16* lp) {
    __builtin_amdgcn_global_load_lds((gu32*)(const void*)gp, (lu32*)(void*)lp,
                                     16, 0, 0);
}
__device__ __forceinline__ void barrier_raw() {
    asm volatile("" ::: "memory");
    __builtin_amdgcn_s_barrier();
    asm volatile("" ::: "memory");
}

// ---------------------------------------------------------------------------
// Fast detector: 256 threads x 8 independent u16x8 loads = 32768 words.
// ---------------------------------------------------------------------------
__global__ void detect_kernel(const u16* __restrict__ x, int* __restrict__ flag)
{
    __shared__ int found;
    if (threadIdx.x == 0) found = 0;
    __syncthreads();
    int local = 0;
    const u16x8* p = (const u16x8*)x + threadIdx.x;
    #pragma unroll
    for (int i = 0; i < 8; ++i) {
        const u16x8 v = p[(size_t)i * 256];
        #pragma unroll
        for (int j = 0; j < 8; ++j)
            if ((v[j] & 0x7F80u) == 0x7F80u) local = 1;
    }
    if (local) atomicOr(&found, 1);
    __syncthreads();
    if (threadIdx.x == 0) *flag = found ? 1 : 0;
}

// ---------------------------------------------------------------------------
// Fused prep: block ranges do {W_attn^T, W_proj^T, x->bf16, biases}.
// ---------------------------------------------------------------------------
__device__ void prep_w_body(const void* __restrict__ Wv, u16* __restrict__ Wt,
                            int K, int N, int bx, int by, int fm,
                            u16 (*Ts)[72])
{
    const int t = threadIdx.x;
    const int n0 = bx * 64, k0 = by * 64;
    const int r = t >> 2, c0 = (t & 3) << 4;

    if (fm) {
        const float* W = (const float*)Wv + (size_t)(k0 + r) * N + n0 + c0;
        #pragma unroll
        for (int i = 0; i < 16; i += 4) {
            const float4 v = *(const float4*)(W + i);
            Ts[c0 + i + 0][r] = f2u(v.x);
            Ts[c0 + i + 1][r] = f2u(v.y);
            Ts[c0 + i + 2][r] = f2u(v.z);
            Ts[c0 + i + 3][r] = f2u(v.w);
        }
    } else {
        const u16* W = (const u16*)Wv + (size_t)(k0 + r) * N + n0 + c0;
        const u16x8 a = *(const u16x8*)W;
        const u16x8 c = *(const u16x8*)(W + 8);
        #pragma unroll
        for (int i = 0; i < 8; ++i) { Ts[c0 + i][r] = a[i]; Ts[c0 + 8 + i][r] = c[i]; }
    }
    __syncthreads();
    u16* o = Wt + (size_t)(n0 + r) * K + k0 + c0;
    *(u16x8*)o = *(const u16x8*)&Ts[r][c0];
    *(u16x8*)(o + 8) = *(const u16x8*)&Ts[r][c0 + 8];
}

__global__ __launch_bounds__(256)
void fused_prep(const void* __restrict__ x, const void* __restrict__ Wa,
                const void* __restrict__ ba, const void* __restrict__ Wp,
                const void* __restrict__ bp,
                u16* __restrict__ xb, u16* __restrict__ WaT,
                u16* __restrict__ WpT, u16* __restrict__ bao,
                u16* __restrict__ bpo,
                const int* __restrict__ flag, int mode)
{
    __shared__ u16 Ts[64][72];
    const int fm = (mode >= 0) ? mode : *flag;
    const int blk = blockIdx.x;
    const int t = threadIdx.x;

    if (blk < 432) {                       // W_attn: grid 36 x 12
        prep_w_body(Wa, WaT, CC, C3, blk % 36, blk / 36, fm, Ts);
    } else if (blk < 576) {                // W_proj: grid 12 x 12
        const int b2 = blk - 432;
        prep_w_body(Wp, WpT, CC, CC, b2 % 12, b2 / 12, fm, Ts);
    } else if (blk < 2112) {               // x -> bf16 (octets), fp32 mode only
        if (fm == 0) return;
        const size_t i = (size_t)(blk - 576) * 256 + t;
        const float* xp = (const float*)x + i * 8;
        u16x8 o;
        #pragma unroll
        for (int j = 0; j < 8; ++j) o[j] = f2u(xp[j]);
        *(u16x8*)(xb + i * 8) = o;
    } else {                               // biases
        const int i = (blk - 2112) * 256 + t;
        if (i < C3) bao[i] = fm ? f2u(((const float*)ba)[i]) : ((const u16*)ba)[i];
        if (i < CC) bpo[i] = fm ? f2u(((const float*)bp)[i]) : ((const u16*)bp)[i];
    }
}

// ---------------------------------------------------------------------------
// MFMA GEMM (round-7 verified, unchanged).
// ---------------------------------------------------------------------------
template <int FRM, int FRN>
__global__ __launch_bounds__(256)
void gemm_mfma(const u16* __restrict__ Adir, const u16* __restrict__ Acnv,
               const u16* __restrict__ Bt, const u16* __restrict__ bias,
               void* __restrict__ outv, int M, int N, int K,
               const int* __restrict__ flag, int mode, int om_sel)
{
    constexpr int TSM = 32 * FRM, TSN = 32 * FRN;
    constexpr int LPA = TSM / 64;
    constexpr int LPB = TSN / 64;

    __shared__ u16 As[2][TSM * 32];
    __shared__ u16 Bs[2][TSN * 32];

    const int fm = (mode >= 0) ? mode : *flag;
    const u16* A = fm ? Acnv : Adir;
    const int om = om_sel ? fm : 0;

    const int nwg = gridDim.x;
    const int lin = (blockIdx.x & 7) * (nwg >> 3) + (blockIdx.x >> 3);
    const int nx = N / TSN;
    const int m0 = (lin / nx) * TSM, n0 = (lin % nx) * TSN;

    const int t = threadIdx.x;
    const int lane = t & 63, wave = t >> 6;
    const int wm = wave >> 1, wn = wave & 1;
    const int l15 = lane & 15, h4 = lane >> 4;

    const int rsub = lane >> 2;
    const int cs = ((lane & 3) ^ ((lane >> 4) & 3)) * 8;
    const u16* Ab[LPA];
    const u16* Bb[LPB];
    #pragma unroll
    for (int j = 0; j < LPA; ++j)
        Ab[j] = A + (size_t)(m0 + wave * (16 * LPA) + j * 16 + rsub) * K + cs;
    #pragma unroll
    for (int j = 0; j < LPB; ++j)
        Bb[j] = Bt + (size_t)(n0 + wave * (16 * LPB) + j * 16 + rsub) * K + cs;

    f32x4 acc[FRM][FRN];
    #pragma unroll
    for (int i = 0; i < FRM; ++i)
        #pragma unroll
        for (int j = 0; j < FRN; ++j) acc[i][j] = (f32x4){0.f, 0.f, 0.f, 0.f};

    const int csr = (h4 ^ (l15 >> 2)) * 8;
    const int arow = wm * (TSM / 2) + l15;
    const int brow = wn * (TSN / 2) + l15;

    const int NT = K >> 5;
    #pragma unroll
    for (int j = 0; j < LPA; ++j)
        gload16(Ab[j], &As[0][(wave * LPA + j) * 512]);
    #pragma unroll
    for (int j = 0; j < LPB; ++j)
        gload16(Bb[j], &Bs[0][(wave * LPB + j) * 512]);

    for (int kt = 0; kt < NT; ++kt) {
        const int cur = kt & 1;
        if (kt + 1 < NT) {
            const int k0 = (kt + 1) << 5;
            const int nb = cur ^ 1;
            #pragma unroll
            for (int j = 0; j < LPA; ++j)
                gload16(Ab[j] + k0, &As[nb][(wave * LPA + j) * 512]);
            #pragma unroll
            for (int j = 0; j < LPB; ++j)
                gload16(Bb[j] + k0, &Bs[nb][(wave * LPB + j) * 512]);
            if constexpr (LPA + LPB == 4)
                asm volatile("s_waitcnt vmcnt(4)" ::: "memory");
            else if constexpr (LPA + LPB == 3)
                asm volatile("s_waitcnt vmcnt(3)" ::: "memory");
            else
                asm volatile("s_waitcnt vmcnt(2)" ::: "memory");
        } else {
            asm volatile("s_waitcnt vmcnt(0)" ::: "memory");
        }
        barrier_raw();

        bf16x8 af[FRM], bfr[FRN];
        #pragma unroll
        for (int f = 0; f < FRM; ++f)
            af[f] = ldsb8(&As[cur][(arow + f * 16) * 32 + csr]);
        #pragma unroll
        for (int f = 0; f < FRN; ++f)
            bfr[f] = ldsb8(&Bs[cur][(brow + f * 16) * 32 + csr]);
        #pragma unroll
        for (int i = 0; i < FRM; ++i)
            #pragma unroll
            for (int j = 0; j < FRN; ++j)
                acc[i][j] = mfma16(af[i], bfr[j], acc[i][j]);

        barrier_raw();
    }

    const int orow = m0 + wm * (TSM / 2) + h4 * 4;
    const int ocol = n0 + wn * (TSN / 2) + l15;
    if (om == 0) {
        u16* out = (u16*)outv;
        #pragma unroll
        for (int i = 0; i < FRM; ++i)
            #pragma unroll
            for (int j = 0; j < FRN; ++j) {
                const int col = ocol + j * 16;
                const float bv = u2f(bias[col]);
                #pragma unroll
                for (int r2 = 0; r2 < 4; ++r2)
                    out[(size_t)(orow + i * 16 + r2) * N + col] = f2b(acc[i][j][r2] + bv);
            }
    } else {
        float* out = (float*)outv;
        #pragma unroll
        for (int i = 0; i < FRM; ++i)
            #pragma unroll
            for (int j = 0; j < FRN; ++j) {
                const int col = ocol + j * 16;
                const float bv = u2f(bias[col]);
                #pragma unroll
                for (int r2 = 0; r2 < 4; ++r2)
                    out[(size_t)(orow + i * 16 + r2) * N + col] = acc[i][j][r2] + bv;
            }
    }
}

// ---------------------------------------------------------------------------
// MFMA flash attention, 32x32x16 shape.
// Wave w: q-half qh=w>>1, k-half kh=w&1 of the 64q x 64k tile.
// S = K·Q^T per wave (32q x 32k): lane owns q = l&31 (col); S rows = k via
// the staging permutation rho: LDS row j holds k = rho(j) = 16j3+8j2+4j4+j1j0
// (stage at rho^-1(k) = 16k2+8k4+4k3+(k&3)). Then PV B-fragments are direct
// reg picks: p0={s0-3,s8-11} (k=8h+i), p1={s4-7,s12-15} (k=16+8h+i).
// Softmax lane-local; defer-max (THR=8) pair-syncs m across l<->l+32 (same q)
// inside the rare branch. k-half waves merged via LDS scratch at epilogue.
// ---------------------------------------------------------------------------
__global__ __launch_bounds__(256)
void attn_mfma(const u16* __restrict__ qkv, u16* __restrict__ yatt)
{
    __shared__ u16 Ks[2][64][72];   // [buf][32*kh + rho^-1(k&31)][d]
    __shared__ u16 Vt[2][64][72];   // [buf][d][k]

    // ---- balanced work assignment (round-3 closed form) ----
    const int bid = blockIdx.x;
    const int bin = bid & 255, slot = bid >> 8;
    const int g = bin >> 5, j = bin & 31;
    int qt;
    if (slot == 0)      qt = j;
    else if (slot == 1) qt = (j + 16) & 31;
    else                qt = (j < 16) ? (30 - 2 * j) : (63 - 2 * j);
    const int hb = slot * 8 + g;
    const int h = hb % HH, b = hb / HH;

    const int t = threadIdx.x;
    const int lane = t & 63, w = t >> 6;
    const int l31 = lane & 31, hl = lane >> 5;
    const int qh = w >> 1, kh = w & 1;
    const int q0 = qt * 64;
    const int qg = q0 + qh * 32 + l31;      // this lane's q row (global)

    // K staging: thread covers original k-row sr, d-cols sd..sd+15;
    // LDS row = 32*(sr>>5) + rho^-1(sr&31).
    const int sr = t >> 2;
    const int sd = (t & 3) << 4;
    const int k5 = sr & 31;
    const int rr = (sr & 32) | (((k5 >> 2) & 1) << 4) | (((k5 >> 4) & 1) << 3)
                 | (((k5 >> 3) & 1) << 2) | (k5 & 3);
    // V staging: packed b32 k-pairs into plain [d][k] (round-7 verified)
    const int vk = (t & 31) * 2;
    const int vd = (t >> 5) << 3;

    // ---- Q in registers (B-operand frags), pre-scaled by 1/8 ----
    bf16x8 qf[4];
    {
        const u16* qp = qkv + ((size_t)(b * TT + qg)) * C3 + h * DD + hl * 8;
        #pragma unroll
        for (int t4 = 0; t4 < 4; ++t4) {
            const u16x8 v = *(const u16x8*)(qp + 16 * t4);
            #pragma unroll
            for (int i = 0; i < 8; ++i)
                qf[t4][i] = (__bf16)(u2f(v[i]) * 0.125f);
        }
    }

    float m_i = -1e4f, l_p = 0.f;
    f32x16 O0, O1;
    #pragma unroll
    for (int i = 0; i < 16; ++i) { O0[i] = 0.f; O1[i] = 0.f; }

    const u16* kB = qkv + ((size_t)(b * TT + sr)) * C3 + CC + h * DD + sd;
    const u16* vB = qkv + ((size_t)(b * TT + vk)) * C3 + 2 * CC + h * DD + vd;

    const int NT = qt + 1;

    // ---- prologue: load+stage tile 0, prefetch tile 1 ----
    u16x8 kr0 = *(const u16x8*)kB;
    u16x8 kr1 = *(const u16x8*)(kB + 8);
    u16x8 vr0 = *(const u16x8*)vB;
    u16x8 vr1 = *(const u16x8*)(vB + C3);
    *(u16x8*)&Ks[0][rr][sd]     = kr0;
    *(u16x8*)&Ks[0][rr][sd + 8] = kr1;
    #pragma unroll
    for (int i = 0; i < 8; ++i)
        *(u32*)&Vt[0][vd + i][vk] = (u32)vr0[i] | ((u32)vr1[i] << 16);
    if (NT > 1) {
        const u16* kp = kB + (size_t)64 * C3;
        const u16* vp = vB + (size_t)64 * C3;
        kr0 = *(const u16x8*)kp;
        kr1 = *(const u16x8*)(kp + 8);
        vr0 = *(const u16x8*)vp;
        vr1 = *(const u16x8*)(vp + C3);
    }
    __syncthreads();

    for (int kt = 0; kt < NT; ++kt) {
        const int cur = kt & 1;

        // ---- S = K Q^T: one 32x32 output, 4 chained depth-mfmas ----
        f32x16 s;
        #pragma unroll
        for (int i = 0; i < 16; ++i) s[i] = 0.f;
        __builtin_amdgcn_s_setprio(1);
        #pragma unroll
        for (int t4 = 0; t4 < 4; ++t4)
            s = mfma32(ldsb8(&Ks[cur][kh * 32 + l31][t4 * 16 + hl * 8]),
                       qf[t4], s);
        __builtin_amdgcn_s_setprio(0);

        // ---- stage tile kt+1; prefetch kt+2 ----
        if (kt + 1 < NT) {
            const int nb = cur ^ 1;
            *(u16x8*)&Ks[nb][rr][sd]     = kr0;
            *(u16x8*)&Ks[nb][rr][sd + 8] = kr1;
            #pragma unroll
            for (int i = 0; i < 8; ++i)
                *(u32*)&Vt[nb][vd + i][vk] = (u32)vr0[i] | ((u32)vr1[i] << 16);
            if (kt + 2 < NT) {
                const u16* kp = kB + (size_t)(kt + 2) * 64 * C3;
                const u16* vp = vB + (size_t)(kt + 2) * 64 * C3;
                kr0 = *(const u16x8*)kp;
                kr1 = *(const u16x8*)(kp + 8);
                vr0 = *(const u16x8*)vp;
                vr1 = *(const u16x8*)(vp + C3);
            }
        }

        // ---- causal mask (diagonal tile); k from the rho map ----
        if (kt == qt) {
            #pragma unroll
            for (int jj = 0; jj < 4; ++jj)
                #pragma unroll
                for (int e = 0; e < 4; ++e) {
                    const int kl = kh * 32 + ((jj & 1) << 4) + (hl << 3)
                                 + ((jj >> 1) << 2) + e;
                    if (kt * 64 + kl > qg) s[4 * jj + e] = -1e30f;
                }
        }

        // ---- softmax, defer-max: lane-local; rare branch pair-syncs m ----
        float pm = s[0];
        #pragma unroll
        for (int i = 1; i < 16; ++i) pm = fmaxf(pm, s[i]);

        if (!__all(pm <= m_i + 8.f)) {
            const float pr = fmaxf(pm, __shfl_xor(pm, 32));   // sync q-pair
            const float mnew = fmaxf(m_i, pr);
            const float a_ = __expf(m_i - mnew);
            l_p *= a_;
            #pragma unroll
            for (int i = 0; i < 16; ++i) { O0[i] *= a_; O1[i] *= a_; }
            m_i = mnew;
        }

        bf16x8 p0, p1;
        float rs = 0.f;
        #pragma unroll
        for (int e = 0; e < 4; ++e) {
            const float a = __expf(s[e] - m_i);       rs += a; p0[e]     = (__bf16)a;
            const float c = __expf(s[8 + e] - m_i);   rs += c; p0[4 + e] = (__bf16)c;
            const float d = __expf(s[4 + e] - m_i);   rs += d; p1[e]     = (__bf16)d;
            const float g2 = __expf(s[12 + e] - m_i); rs += g2; p1[4 + e] = (__bf16)g2;
        }
        l_p += rs;

        // ---- O += P V  (V-frag A-operand from plain Vt[d][k]) ----
        __builtin_amdgcn_s_setprio(1);
        O0 = mfma32(ldsb8(&Vt[cur][l31][kh * 32 + hl * 8]), p0, O0);
        O0 = mfma32(ldsb8(&Vt[cur][l31][kh * 32 + 16 + hl * 8]), p1, O0);
        O1 = mfma32(ldsb8(&Vt[cur][32 + l31][kh * 32 + hl * 8]), p0, O1);
        O1 = mfma32(ldsb8(&Vt[cur][32 + l31][kh * 32 + 16 + hl * 8]), p1, O1);
        __builtin_amdgcn_s_setprio(0);

        __syncthreads();                   // one barrier per tile
    }

    // ---- epilogue: pair-sum l, merge k-half waves via LDS, store ----
    const float lr = l_p + __shfl_xor(l_p, 32);       // q-total (m pair-synced)

    float* scr = (float*)&Ks[0][0][0];                // 17.4KB scratch (done w/ Ks)
    const int sidx = (qh * 64 + lane) * 34;
    if (kh == 1) {
        scr[sidx] = m_i;
        scr[sidx + 1] = lr;
        #pragma unroll
        for (int i = 0; i < 16; ++i) {
            scr[sidx + 2 + i] = O0[i];
            scr[sidx + 18 + i] = O1[i];
        }
    }
    __syncthreads();
    if (kh == 0) {
        const float mB = scr[sidx], lB = scr[sidx + 1];
        const float mm = fmaxf(m_i, mB);
        const float a0 = __expf(m_i - mm), a1 = __expf(mB - mm);
        const float inv = 1.0f / (lr * a0 + lB * a1);
        u16* yp = yatt + ((size_t)(b * TT + qg)) * CC + h * DD;
        #pragma unroll
        for (int r = 0; r < 16; ++r) {
            const int drow = (r & 3) + 8 * (r >> 2) + 4 * hl;
            yp[drow]      = f2b((O0[r] * a0 + scr[sidx + 2 + r] * a1) * inv);
            yp[32 + drow] = f2b((O1[r] * a0 + scr[sidx + 18 + r] * a1) * inv);
        }
    }
}

// ---------------------------------------------------------------------------
extern "C" void kernel_launch(void* const* d_in, const int* in_sizes, int n_in,
                              void* d_out, int out_size, void* d_ws, size_t ws_size,
                              hipStream_t stream)
{
    (void)n_in; (void)out_size; (void)ws_size;

    const void* x      = d_in[0];
    const void* W_attn = d_in[1];
    const void* b_attn = d_in[2];
    const void* W_proj = d_in[3];
    const void* b_proj = d_in[4];

    // workspace layout (~30 MB)
    u16* qkv  = (u16*)d_ws;                       // [4096,2304] bf16
    u16* yatt = qkv + (size_t)MM * C3;            // [4096,768]  bf16
    u16* xb   = yatt;                             // bf16 x — lifetime disjoint
    u16* WaT  = yatt + (size_t)MM * CC;           // [2304,768]  bf16 (W_attn^T)
    u16* WpT  = WaT + (size_t)C3 * CC;            // [768,768]   bf16 (W_proj^T)
    u16* ba   = WpT + (size_t)CC * CC;            // [2304] bf16
    u16* bp   = ba + C3;                          // [768]  bf16
    int* flag = (int*)(bp + CC);                  // 1 int

    // host-side dtype inference from byte sizes; device detector as fallback
    int mode = -1;
    if (in_sizes[0] == MM * CC * 4) mode = 1;          // fp32 bytes
    else if (in_sizes[0] == MM * CC * 2) mode = 0;     // bf16 bytes
    if (mode < 0) {
        detect_kernel<<<1, 256, 0, stream>>>((const u16*)x, flag);
    }

    // fused prep: W transposes + x->bf16 (fp32 mode only) + biases
    fused_prep<<<2121, 256, 0, stream>>>(x, W_attn, b_attn, W_proj, b_proj,
                                         xb, WaT, WpT, ba, bp, flag, mode);

    // 1) qkv = x/xb @ W_attn + b_attn (bf16 out), 128x64 tiles, 1152 blocks
    gemm_mfma<4, 2><<<(MM / 128) * (C3 / 64), 256, 0, stream>>>(
        (const u16*)x, xb, WaT, ba, (void*)qkv, MM, C3, CC, flag, mode, 0);

    // 2) causal flash attention (32x32 mfma)
    attn_mfma<<<dim3(TT / 64 * HH * BB, 1, 1), 256, 0, stream>>>(qkv, yatt);

    // 3) out = yatt @ W_proj + b_proj (out dtype follows mode), 64x64 tiles
    gemm_mfma<2, 2><<<(MM / 64) * (CC / 64), 256, 0, stream>>>(
        yatt, yatt, WpT, bp, d_out, MM, CC, CC, flag, mode, 1);
}